// Round 13
// baseline (494.948 us; speedup 1.0000x reference)
//
#include <hip/hip_runtime.h>

#define NN 4096
#define HH 256
#define EE 131072

__device__ __constant__ float LN_EPS = 1e-5f;
#define ATT_SCALE 0.08838834764831845f
#define ATT_SHIFT 30.0f

typedef __attribute__((ext_vector_type(8))) short bf16x8_t;
typedef __attribute__((ext_vector_type(4))) float f32x4_t;

__device__ inline ushort f2b(float f) {
  uint u = __float_as_uint(f);
  uint r = (u + 0x7FFF + ((u >> 16) & 1)) >> 16;
  return (ushort)r;
}
__device__ inline float b2f(ushort u) { return __uint_as_float((uint)u << 16); }

// ---------------- CSR build ----------------
__global__ void hist_kernel(const int* __restrict__ ei, int* __restrict__ cnt) {
  int e = blockIdx.x * blockDim.x + threadIdx.x;
  if (e < EE) atomicAdd(&cnt[ei[EE + e]], 1);
}

__global__ __launch_bounds__(1024) void scan_kernel(int* __restrict__ cnt_cursor,
                                                    int* __restrict__ rowptr,
                                                    float* __restrict__ invdeg) {
  __shared__ int part[1024];
  int t = threadIdx.x;
  int base = t * 4;
  int cs[4];
  int s = 0;
  for (int u = 0; u < 4; ++u) { cs[u] = cnt_cursor[base + u]; s += cs[u]; }
  part[t] = s;
  __syncthreads();
  for (int off = 1; off < 1024; off <<= 1) {
    int add = (t >= off) ? part[t - off] : 0;
    int v = part[t];
    __syncthreads();
    part[t] = v + add;
    __syncthreads();
  }
  int excl = (t > 0) ? part[t - 1] : 0;
  for (int u = 0; u < 4; ++u) {
    rowptr[base + u] = excl;
    cnt_cursor[base + u] = excl;
    invdeg[base + u] = 1.0f / (float)max(cs[u], 1);
    excl += cs[u];
  }
  if (t == 1023) rowptr[NN] = excl;
}

__global__ void fill_kernel(const int* __restrict__ ei, int* __restrict__ cursor,
                            int* __restrict__ col) {
  int e = blockIdx.x * blockDim.x + threadIdx.x;
  if (e < EE) {
    int d = ei[EE + e];
    int p = atomicAdd(&cursor[d], 1);
    col[p] = ei[e];
  }
}

// ---------------- all weight casts in ONE launch ----------------
__global__ __launch_bounds__(256) void castall(
    const float* __restrict__ wl, const float* __restrict__ wr,
    const float* __restrict__ cw, const float* __restrict__ ip,
    const float* __restrict__ opw,
    ushort* __restrict__ wlb, ushort* __restrict__ wrb, ushort* __restrict__ cvb,
    ushort* __restrict__ ipb, ushort* __restrict__ opb) {
  int i4 = (blockIdx.x * 256 + threadIdx.x) * 4;
  if (i4 >= 2424832) return;
  ushort4 o;
  if (i4 < 393216) {
    float4 v = *(const float4*)(wl + i4);
    o.x = f2b(v.x); o.y = f2b(v.y); o.z = f2b(v.z); o.w = f2b(v.w);
    *(ushort4*)(wlb + i4) = o;
  } else if (i4 < 786432) {
    int p = i4 - 393216;
    float4 v = *(const float4*)(wr + p);
    o.x = f2b(v.x); o.y = f2b(v.y); o.z = f2b(v.z); o.w = f2b(v.w);
    *(ushort4*)(wrb + p) = o;
  } else if (i4 < 1376256) {
    int p = i4 - 786432;
    ushort tmp[4];
#pragma unroll
    for (int u = 0; u < 4; ++u) {
      int idx = p + u;
      int j = idx / 196608;
      int rem = idx - j * 196608;
      int oc = rem / 768;
      int kk = rem - oc * 768;
      int ks = kk >> 8, ii = kk & 255;
      tmp[u] = f2b(cw[j * 196608 + oc * 768 + ii * 3 + ks]);
    }
    o.x = tmp[0]; o.y = tmp[1]; o.z = tmp[2]; o.w = tmp[3];
    *(ushort4*)(cvb + p) = o;
  } else if (i4 < 2162688) {
    int p = i4 - 1376256;
    float4 v = *(const float4*)(ip + p);
    o.x = f2b(v.x); o.y = f2b(v.y); o.z = f2b(v.z); o.w = f2b(v.w);
    *(ushort4*)(ipb + p) = o;
  } else {
    int p = i4 - 2162688;
    float4 v = *(const float4*)(opw + p);
    o.x = f2b(v.x); o.y = f2b(v.y); o.z = f2b(v.z); o.w = f2b(v.w);
    *(ushort4*)(opb + p) = o;
  }
}

// ---------------- x -> h (fp32 copy) + hb (bf16) ----------------
__global__ __launch_bounds__(256) void copycast(const float* __restrict__ x,
                                                float* __restrict__ h,
                                                ushort* __restrict__ hb) {
  int i4 = (blockIdx.x * 256 + threadIdx.x) * 4;
  float4 v = *(const float4*)(x + i4);
  *(float4*)(h + i4) = v;
  ushort4 w;
  w.x = f2b(v.x); w.y = f2b(v.y); w.z = f2b(v.z); w.w = f2b(v.w);
  *(ushort4*)(hb + i4) = w;
}

// ---------------- neighbor mean aggregation (bf16 in, fp32 acc, bf16 out) ----------------
__global__ __launch_bounds__(64) void agg_kernel(const ushort* __restrict__ hb,
                                                 const int* __restrict__ rowptr,
                                                 const int* __restrict__ col,
                                                 const float* __restrict__ invdeg,
                                                 ushort* __restrict__ aggb) {
  int n = blockIdx.x;
  int t = threadIdx.x;
  int s = rowptr[n], e = rowptr[n + 1];
  float4 acc = make_float4(0.f, 0.f, 0.f, 0.f);
  for (int j = s; j < e; ++j) {
    int c = col[j];
    ushort4 v = *(const ushort4*)(hb + (size_t)c * HH + t * 4);
    acc.x += b2f(v.x); acc.y += b2f(v.y); acc.z += b2f(v.z); acc.w += b2f(v.w);
  }
  float id = invdeg[n];
  ushort4 w;
  w.x = f2b(acc.x * id); w.y = f2b(acc.y * id);
  w.z = f2b(acc.z * id); w.w = f2b(acc.w * id);
  *(ushort4*)(aggb + (size_t)n * HH + t * 4) = w;
}

// ---------------- bf16 MFMA GEMM: C[M,Nn] = A[M,K] B[Nn,K]^T + bias ----------------
__global__ __launch_bounds__(256) void gemm_mfma(
    const ushort* __restrict__ A0, const ushort* __restrict__ A1,
    const ushort* __restrict__ B0, const ushort* __restrict__ B1,
    const float* __restrict__ bias, float* __restrict__ Cf, ushort* __restrict__ Cb,
    int M, int Nn, int K, int KHA, int KHB, int relu) {
  __shared__ ushort Alds[64][40];
  __shared__ ushort Blds[128][40];
  int t = threadIdx.x;
  int w = t >> 6, l = t & 63, quad = l >> 4, lr = l & 15;
  int wm = w & 1, wn = w >> 1;
  int m0 = blockIdx.x * 64, n0 = blockIdx.y * 128;
  int sr = t >> 2, sc8 = (t & 3) * 8;
  f32x4_t acc[2][4];
#pragma unroll
  for (int s = 0; s < 2; ++s)
#pragma unroll
    for (int q = 0; q < 4; ++q) acc[s][q] = (f32x4_t){0.f, 0.f, 0.f, 0.f};

  for (int k0 = 0; k0 < K; k0 += 32) {
    int kk = k0 + sc8;
    const ushort* ap = (kk < KHA) ? (A0 + (size_t)(m0 + sr) * KHA + kk)
                                  : (A1 + (size_t)(m0 + sr) * (K - KHA) + (kk - KHA));
    uint4 av = *(const uint4*)ap;
    const ushort* bp0 = (kk < KHB) ? (B0 + (size_t)(n0 + sr) * KHB + kk)
                                   : (B1 + (size_t)(n0 + sr) * (K - KHB) + (kk - KHB));
    uint4 bv0 = *(const uint4*)bp0;
    const ushort* bp1 = (kk < KHB) ? (B0 + (size_t)(n0 + 64 + sr) * KHB + kk)
                                   : (B1 + (size_t)(n0 + 64 + sr) * (K - KHB) + (kk - KHB));
    uint4 bv1 = *(const uint4*)bp1;
    __syncthreads();
    *(uint4*)&Alds[sr][sc8] = av;
    *(uint4*)&Blds[sr][sc8] = bv0;
    *(uint4*)&Blds[64 + sr][sc8] = bv1;
    __syncthreads();
    bf16x8_t af[2], bf[4];
#pragma unroll
    for (int s = 0; s < 2; ++s)
      af[s] = *(const bf16x8_t*)&Alds[wm * 32 + s * 16 + lr][quad * 8];
#pragma unroll
    for (int q = 0; q < 4; ++q)
      bf[q] = *(const bf16x8_t*)&Blds[wn * 64 + q * 16 + lr][quad * 8];
#pragma unroll
    for (int s = 0; s < 2; ++s)
#pragma unroll
      for (int q = 0; q < 4; ++q)
        acc[s][q] = __builtin_amdgcn_mfma_f32_16x16x32_bf16(af[s], bf[q], acc[s][q], 0, 0, 0);
  }
#pragma unroll
  for (int s = 0; s < 2; ++s) {
#pragma unroll
    for (int q = 0; q < 4; ++q) {
      int n = n0 + wn * 64 + q * 16 + lr;
      float bb = bias[n];
#pragma unroll
      for (int r = 0; r < 4; ++r) {
        int m = m0 + wm * 32 + s * 16 + quad * 4 + r;
        float v = acc[s][q][r] + bb;
        if (relu) v = fmaxf(v, 0.f);
        if (Cf) Cf[(size_t)m * Nn + n] = v;
        if (Cb) Cb[(size_t)m * Nn + n] = f2b(v);
      }
    }
  }
}

// ---------------- dual independent 256x256 GEMMs (SAGE layer), z picks operand set ----------------
__global__ __launch_bounds__(256) void gemm_dual(
    const ushort* __restrict__ A0, const ushort* __restrict__ B0,
    const float* __restrict__ bias0, float* __restrict__ C0,
    const ushort* __restrict__ A1, const ushort* __restrict__ B1,
    float* __restrict__ C1) {
  __shared__ ushort Alds[64][40];
  __shared__ ushort Blds[128][40];
  int t = threadIdx.x;
  int w = t >> 6, l = t & 63, quad = l >> 4, lr = l & 15;
  int wm = w & 1, wn = w >> 1;
  int m0 = blockIdx.x * 64, n0 = blockIdx.y * 128;
  int z = blockIdx.z;
  const ushort* A = z ? A1 : A0;
  const ushort* B = z ? B1 : B0;
  float* C = z ? C1 : C0;
  int sr = t >> 2, sc8 = (t & 3) * 8;
  f32x4_t acc[2][4];
#pragma unroll
  for (int s = 0; s < 2; ++s)
#pragma unroll
    for (int q = 0; q < 4; ++q) acc[s][q] = (f32x4_t){0.f, 0.f, 0.f, 0.f};

  for (int k0 = 0; k0 < 256; k0 += 32) {
    int kk = k0 + sc8;
    uint4 av = *(const uint4*)(A + (size_t)(m0 + sr) * 256 + kk);
    uint4 bv0 = *(const uint4*)(B + (size_t)(n0 + sr) * 256 + kk);
    uint4 bv1 = *(const uint4*)(B + (size_t)(n0 + 64 + sr) * 256 + kk);
    __syncthreads();
    *(uint4*)&Alds[sr][sc8] = av;
    *(uint4*)&Blds[sr][sc8] = bv0;
    *(uint4*)&Blds[64 + sr][sc8] = bv1;
    __syncthreads();
    bf16x8_t af[2], bf[4];
#pragma unroll
    for (int s = 0; s < 2; ++s)
      af[s] = *(const bf16x8_t*)&Alds[wm * 32 + s * 16 + lr][quad * 8];
#pragma unroll
    for (int q = 0; q < 4; ++q)
      bf[q] = *(const bf16x8_t*)&Blds[wn * 64 + q * 16 + lr][quad * 8];
#pragma unroll
    for (int s = 0; s < 2; ++s)
#pragma unroll
      for (int q = 0; q < 4; ++q)
        acc[s][q] = __builtin_amdgcn_mfma_f32_16x16x32_bf16(af[s], bf[q], acc[s][q], 0, 0, 0);
  }
#pragma unroll
  for (int s = 0; s < 2; ++s) {
#pragma unroll
    for (int q = 0; q < 4; ++q) {
      int n = n0 + wn * 64 + q * 16 + lr;
      float bb = z ? 0.f : bias0[n];
#pragma unroll
      for (int r = 0; r < 4; ++r) {
        int m = m0 + wm * 32 + s * 16 + quad * 4 + r;
        C[(size_t)m * 256 + n] = acc[s][q][r] + bb;
      }
    }
  }
}

// ---------------- conv1d(k=3,pad=1) as MFMA GEMM, z-split K (2x384), raw fp32 out ----------------
__global__ __launch_bounds__(256) void gemm_conv_mfma(
    const ushort* __restrict__ Ab, const ushort* __restrict__ B,
    const float* __restrict__ bias, float* __restrict__ C0, float* __restrict__ C1) {
  __shared__ ushort Alds[64][40];
  __shared__ ushort Blds[128][40];
  int t = threadIdx.x;
  int w = t >> 6, l = t & 63, quad = l >> 4, lr = l & 15;
  int wm = w & 1, wn = w >> 1;
  int m0 = blockIdx.x * 64, n0 = blockIdx.y * 128;
  int z = blockIdx.z;
  float* C = z ? C1 : C0;
  int sr = t >> 2, sc8 = (t & 3) * 8;
  f32x4_t acc[2][4];
#pragma unroll
  for (int s = 0; s < 2; ++s)
#pragma unroll
    for (int q = 0; q < 4; ++q) acc[s][q] = (f32x4_t){0.f, 0.f, 0.f, 0.f};

  for (int k0 = 0; k0 < 384; k0 += 32) {
    int kk = z * 384 + k0 + sc8;
    int ks = kk >> 8, ii = kk & 255;
    int nr = m0 + sr + ks - 1;
    uint4 av = make_uint4(0u, 0u, 0u, 0u);
    if (nr >= 0 && nr < NN) av = *(const uint4*)(Ab + (size_t)nr * HH + ii);
    uint4 bv0 = *(const uint4*)(B + (size_t)(n0 + sr) * 768 + kk);
    uint4 bv1 = *(const uint4*)(B + (size_t)(n0 + 64 + sr) * 768 + kk);
    __syncthreads();
    *(uint4*)&Alds[sr][sc8] = av;
    *(uint4*)&Blds[sr][sc8] = bv0;
    *(uint4*)&Blds[64 + sr][sc8] = bv1;
    __syncthreads();
    bf16x8_t af[2], bf[4];
#pragma unroll
    for (int s = 0; s < 2; ++s)
      af[s] = *(const bf16x8_t*)&Alds[s * 16 + wm * 32 + lr][quad * 8];
#pragma unroll
    for (int q = 0; q < 4; ++q)
      bf[q] = *(const bf16x8_t*)&Blds[wn * 64 + q * 16 + lr][quad * 8];
#pragma unroll
    for (int s = 0; s < 2; ++s)
#pragma unroll
      for (int q = 0; q < 4; ++q)
        acc[s][q] = __builtin_amdgcn_mfma_f32_16x16x32_bf16(af[s], bf[q], acc[s][q], 0, 0, 0);
  }
#pragma unroll
  for (int s = 0; s < 2; ++s) {
#pragma unroll
    for (int q = 0; q < 4; ++q) {
      int n = n0 + wn * 64 + q * 16 + lr;
      float bb = z ? 0.f : bias[n];
#pragma unroll
      for (int r = 0; r < 4; ++r) {
        int m = m0 + wm * 32 + s * 16 + quad * 4 + r;
        C[(size_t)m * HH + n] = acc[s][q][r] + bb;
      }
    }
  }
}

// ---------------- fp32 tiled GEMM (fuse head only) ----------------
__global__ __launch_bounds__(256) void gemm_std(
    const float* __restrict__ A0, const float* __restrict__ B0,
    const float* __restrict__ bias, float* __restrict__ C,
    int M, int Nn, int K) {
  __shared__ float As[16][68];
  __shared__ float Bs[16][68];
  int t = threadIdx.x;
  int m0 = blockIdx.x * 64, n0 = blockIdx.y * 64;
  int ty = t >> 4, tx = t & 15;
  int lr = t >> 2, lc4 = (t & 3) * 4;
  float acc[4][4] = {};
  for (int k0 = 0; k0 < K; k0 += 16) {
    int kk = k0 + lc4;
    float4 va = *(const float4*)(A0 + (size_t)(m0 + lr) * K + kk);
    As[lc4 + 0][lr] = va.x; As[lc4 + 1][lr] = va.y;
    As[lc4 + 2][lr] = va.z; As[lc4 + 3][lr] = va.w;
    float4 vb = *(const float4*)(B0 + (size_t)(n0 + lr) * K + kk);
    Bs[lc4 + 0][lr] = vb.x; Bs[lc4 + 1][lr] = vb.y;
    Bs[lc4 + 2][lr] = vb.z; Bs[lc4 + 3][lr] = vb.w;
    __syncthreads();
#pragma unroll
    for (int k = 0; k < 16; ++k) {
      float4 a4 = *(const float4*)&As[k][4 * ty];
      float4 b4 = *(const float4*)&Bs[k][4 * tx];
      float av[4] = {a4.x, a4.y, a4.z, a4.w};
      float bv[4] = {b4.x, b4.y, b4.z, b4.w};
#pragma unroll
      for (int i = 0; i < 4; ++i)
#pragma unroll
        for (int j = 0; j < 4; ++j) acc[i][j] += av[i] * bv[j];
    }
    __syncthreads();
  }
#pragma unroll
  for (int i = 0; i < 4; ++i) {
    int m = m0 + 4 * ty + i;
    float o[4];
#pragma unroll
    for (int j = 0; j < 4; ++j) o[j] = acc[i][j] + bias[n0 + 4 * tx + j];
    float4 o4 = make_float4(o[0], o[1], o[2], o[3]);
    *(float4*)(C + (size_t)m * Nn + n0 + 4 * tx) = o4;
  }
}

// ---------------- fused LayerNorm (+ x2 sum + pre-relu + optional relu+residual) ----------------
__global__ __launch_bounds__(256) void ln_fuse(
    const float* __restrict__ x, const float* __restrict__ x2,
    const float* __restrict__ g, const float* __restrict__ b,
    const float* __restrict__ res, float* __restrict__ outf, ushort* __restrict__ outb,
    int D, int do_ln, int relu_res, int prerelu) {
  int row = blockIdx.x, t = threadIdx.x;
  int nv = D >> 8;
  float vals[2];
  float s = 0.f, sq = 0.f;
  for (int u = 0; u < nv; ++u) {
    int c = t + (u << 8);
    float v = x[(size_t)row * D + c];
    if (x2) v += x2[(size_t)row * D + c];
    if (prerelu) v = fmaxf(v, 0.f);
    vals[u] = v; s += v; sq += v * v;
  }
  __shared__ float red[8];
  float m = 0.f, inv = 1.f;
  if (do_ln) {
    for (int off = 32; off >= 1; off >>= 1) {
      s += __shfl_xor(s, off);
      sq += __shfl_xor(sq, off);
    }
    int wid = t >> 6;
    if ((t & 63) == 0) { red[wid] = s; red[4 + wid] = sq; }
    __syncthreads();
    if (t == 0) {
      float S = red[0] + red[1] + red[2] + red[3];
      float Q = red[4] + red[5] + red[6] + red[7];
      float mm = S / D;
      float vv = Q / D - mm * mm;
      red[0] = mm;
      red[1] = rsqrtf(vv + LN_EPS);
    }
    __syncthreads();
    m = red[0]; inv = red[1];
  }
  for (int u = 0; u < nv; ++u) {
    int c = t + (u << 8);
    float y = vals[u];
    if (do_ln) y = (y - m) * inv * g[c] + b[c];
    if (relu_res) y = fmaxf(y, 0.f) + res[(size_t)row * D + c];
    if (outf) outf[(size_t)row * D + c] = y;
    if (outb) outb[(size_t)row * D + c] = f2b(y);
  }
}

// ---------------- K/V repack for shared-K attention ----------------
// Kt[head][kt] = 8KB tile, fragment-packed LANE-LINEAR: frag (ks,ct) at ushort
// offset (ks*2+ct)*512 + l*8 holds K[key=n0+ct*16+(l&15)][head*128+ks*32+(l>>4)*8..+8].
// VtT[head][kt][dl][key32] unchanged (1KB contiguous per dt fragment).
__global__ __launch_bounds__(256) void kvpack(const ushort* __restrict__ qkvb,
                                              ushort* __restrict__ Kt,
                                              ushort* __restrict__ VtT) {
  int t = threadIdx.x;
  int n0 = blockIdx.x * 32;
  int by = blockIdx.y;
  int kt = n0 >> 5;
  // K repack (lane-linear fragments)
  {
    int head = by >> 2, ks = by & 3;
    int key5 = t >> 3;            // 0..31
    int ct = key5 >> 4, lr = key5 & 15;
    int e8 = t & 7;
    int quad = e8 >> 1, h4 = (e8 & 1) * 4;
    uint2 v = *(const uint2*)(qkvb + (size_t)(n0 + key5) * 1536 + 512 + head * 128 +
                              ks * 32 + quad * 8 + h4);
    int l = quad * 16 + lr;
    *(uint2*)(Kt + (((size_t)head * 128 + kt) << 12) + (ks * 2 + ct) * 512 + l * 8 + h4) = v;
  }
  // V transpose (unchanged)
  __shared__ ushort tile[32][34];
  int d0 = by * 32;
  int tx = t & 31, ty = t >> 5;
#pragma unroll
  for (int u = 0; u < 4; ++u) {
    int r = ty + 8 * u;
    tile[r][tx] = qkvb[(size_t)(n0 + r) * 1536 + 1024 + d0 + tx];
  }
  __syncthreads();
#pragma unroll
  for (int u = 0; u < 4; ++u) {
    int dg = d0 + ty + 8 * u;
    int head = dg >> 7, dl = dg & 127;
    VtT[((((size_t)head * 128 + kt) * 128 + dl) << 5) + tx] = tile[tx][ty + 8 * u];
  }
}

// ---------------- bf16 MFMA flash attention v13: Qb=128, 8 waves, shared-K ----------------
// R11's proven schedule (QK -> exp -> barrier -> PV -> commit -> barrier) + R12's
// conflict-free stride-16B staging, with 128 q-rows per 512-thread block:
// each staged K byte now serves 128 rows -> L2 traffic 256MB (R11: 512MB).
// Wave w owns q-rows [16w,16w+16) for QK/softmax and d-cols [16w,16w+16) for PV
// (one V fragment per tile per wave; every output element owned by one wave).
// Grid (32,4,2)=256 blocks = 1 block/CU = 8 waves/CU = 2 waves/SIMD (same as R11).
__global__ __launch_bounds__(512, 2) void attn_mfma(const ushort* __restrict__ qkvb,
                                                    const ushort* __restrict__ Kt,
                                                    const ushort* __restrict__ VtT,
                                                    ushort* __restrict__ Opart,
                                                    float* __restrict__ Dpart) {
  __shared__ __align__(16) char smem[26624];  // Kl[2][4096]u (16KB) + Psh[8][16][40]u (10240B)
  ushort* Kl = (ushort*)smem;
  ushort* Psh = (ushort*)(smem + 16384);
  int t = threadIdx.x;
  int w = t >> 6, l = t & 63;
  int quad = l >> 4, lr = l & 15;
  int head = blockIdx.y;
  int z = blockIdx.z;
  int q0 = blockIdx.x * 128;

  // Q fragments: wave w's 16 rows x 4 k-slices
  bf16x8_t qf[4];
#pragma unroll
  for (int ks = 0; ks < 4; ++ks)
    qf[ks] = *(const bf16x8_t*)(qkvb + (size_t)(q0 + w * 16 + lr) * 1536 +
                                head * 128 + ks * 32 + quad * 8);

  f32x4_t of[8];  // O[rc*16 rows][w's 16 cols]
#pragma unroll
  for (int rc = 0; rc < 8; ++rc) of[rc] = (f32x4_t){0.f, 0.f, 0.f, 0.f};
  float den[4] = {0.f, 0.f, 0.f, 0.f};

  const size_t hk = (size_t)head * 128;
  // prologue: stage first K tile into Kl[0] (512 threads x 16B, stride-16: conflict-free)
  {
    const ushort* kb = Kt + ((hk + z * 64) << 12);
    *(uint4*)(Kl + t * 8) = *(const uint4*)(kb + t * 8);
  }
  __syncthreads();
  int cur = 0;

  for (int tt = 0; tt < 64; ++tt) {
    int kt = z * 64 + tt;
    // prefetch next K tile into registers (4 VGPR; committed after PV)
    uint4 kpre;
    if (tt < 63) {
      kpre = *(const uint4*)(Kt + ((hk + kt + 1) << 12) + t * 8);
    }
    // V fragment for this wave's 16 d-cols (global, 1KB coalesced)
    bf16x8_t vf = *(const bf16x8_t*)(VtT + ((hk + kt) << 12) + w * 512 + lr * 32 + quad * 8);

    // QK^T: S[w's 16 rows][32 keys]
    f32x4_t sf[2];
    sf[0] = (f32x4_t){0.f, 0.f, 0.f, 0.f};
    sf[1] = (f32x4_t){0.f, 0.f, 0.f, 0.f};
    __builtin_amdgcn_s_setprio(1);
#pragma unroll
    for (int ks = 0; ks < 4; ++ks)
#pragma unroll
      for (int ct = 0; ct < 2; ++ct) {
        bf16x8_t kf = *(const bf16x8_t*)(Kl + cur * 4096 + (ks * 2 + ct) * 512 + l * 8);
        sf[ct] = __builtin_amdgcn_mfma_f32_16x16x32_bf16(qf[ks], kf, sf[ct], 0, 0, 0);
      }
    __builtin_amdgcn_s_setprio(0);

    // softmax exp (fixed shift): P -> shared LDS, den partials
#pragma unroll
    for (int ct = 0; ct < 2; ++ct)
#pragma unroll
      for (int r = 0; r < 4; ++r) {
        float e = __expf(sf[ct][r] * ATT_SCALE - ATT_SHIFT);
        Psh[w * 640 + (quad * 4 + r) * 40 + ct * 16 + lr] = f2b(e);
        den[r] += e;
      }
    __syncthreads();  // P visible to all waves; all QK reads of Kl[cur] done

    // PV: O[all 128 rows][w's 16 cols] += P * V
    __builtin_amdgcn_s_setprio(1);
#pragma unroll
    for (int rc = 0; rc < 8; ++rc) {
      bf16x8_t pf = *(const bf16x8_t*)(Psh + rc * 640 + lr * 40 + quad * 8);
      of[rc] = __builtin_amdgcn_mfma_f32_16x16x32_bf16(pf, vf, of[rc], 0, 0, 0);
    }
    __builtin_amdgcn_s_setprio(0);

    // commit prefetched K to the other buffer
    if (tt < 63) {
      *(uint4*)(Kl + (cur ^ 1) * 4096 + t * 8) = kpre;
    }
    __syncthreads();  // Kl[cur^1] ready; Psh consumed (safe to overwrite next iter)
    cur ^= 1;
  }

  // den: reduce over the 16 lr lanes (rows quad*4+r of wave w)
#pragma unroll
  for (int mask = 1; mask < 16; mask <<= 1)
#pragma unroll
    for (int r = 0; r < 4; ++r) den[r] += __shfl_xor(den[r], mask);
  if (lr == 0) {
#pragma unroll
    for (int r = 0; r < 4; ++r)
      Dpart[((size_t)z * NN + q0 + w * 16 + quad * 4 + r) * 4 + head] = den[r];
  }
  // O partial write: each (row, col) owned by exactly one (wave, lane)
#pragma unroll
  for (int rc = 0; rc < 8; ++rc)
#pragma unroll
    for (int r = 0; r < 4; ++r) {
      int row = q0 + rc * 16 + quad * 4 + r;
      int colg = head * 128 + w * 16 + lr;
      Opart[((size_t)z * NN + row) * 512 + colg] = f2b(of[rc][r]);
    }
}

// ---------------- combine the two k-halves: aob = (O0+O1)/(d0+d1), bf16 ----------------
__global__ __launch_bounds__(256) void attn_merge(const ushort* __restrict__ Opart,
                                                  const float* __restrict__ Dpart,
                                                  ushort* __restrict__ aob) {
  int i8 = (blockIdx.x * 256 + threadIdx.x) * 8;
  int row = i8 >> 9, colg = i8 & 511;
  int head = colg >> 7;
  float inv = 1.f / (Dpart[(size_t)row * 4 + head] + Dpart[((size_t)NN + row) * 4 + head]);
  const ushort4* p0 = (const ushort4*)(Opart + (size_t)row * 512 + colg);
  const ushort4* p1 = (const ushort4*)(Opart + ((size_t)NN + row) * 512 + colg);
  ushort4 o[2];
#pragma unroll
  for (int u = 0; u < 2; ++u) {
    ushort4 a = p0[u], b = p1[u];
    o[u].x = f2b((b2f(a.x) + b2f(b.x)) * inv);
    o[u].y = f2b((b2f(a.y) + b2f(b.y)) * inv);
    o[u].z = f2b((b2f(a.z) + b2f(b.z)) * inv);
    o[u].w = f2b((b2f(a.w) + b2f(b.w)) * inv);
  }
  *(ushort4*)(aob + (size_t)row * 512 + colg) = o[0];
  *(ushort4*)(aob + (size_t)row * 512 + colg + 4) = o[1];
}

// ---------------- launch ----------------
extern "C" void kernel_launch(void* const* d_in, const int* in_sizes, int n_in,
                              void* d_out, int out_size, void* d_ws, size_t ws_size,
                              hipStream_t stream) {
  const float* x          = (const float*)d_in[0];
  const int*   ei         = (const int*)d_in[1];
  const float* sage_wl    = (const float*)d_in[2];
  const float* sage_wr    = (const float*)d_in[3];
  const float* sage_bl    = (const float*)d_in[4];
  const float* ln_g       = (const float*)d_in[5];
  const float* ln_b       = (const float*)d_in[6];
  const float* conv_w     = (const float*)d_in[7];
  const float* conv_b     = (const float*)d_in[8];
  const float* cnorm_g    = (const float*)d_in[9];
  const float* cnorm_b    = (const float*)d_in[10];
  const float* in_proj_w  = (const float*)d_in[11];
  const float* in_proj_b  = (const float*)d_in[12];
  const float* out_proj_w = (const float*)d_in[13];
  const float* out_proj_b = (const float*)d_in[14];
  const float* anorm_g    = (const float*)d_in[15];
  const float* anorm_b    = (const float*)d_in[16];
  const float* fuse_w     = (const float*)d_in[17];
  const float* fuse_b     = (const float*)d_in[18];
  float* out = (float*)d_out;

  char* ws = (char*)d_ws;
  const size_t MB = 1 << 20;
  int*    rowptr = (int*)(ws + 0);
  int*    cnt    = (int*)(ws + 65536);
  int*    col    = (int*)(ws + 131072);
  float*  invdeg = (float*)(ws + 786432);
  float*  Dpart  = (float*)(ws + 802816);   // 2*4096*4*4B = 128KB
  float*  h    = (float*)(ws + 1 * MB);
  ushort* hb   = (ushort*)(ws + 5 * MB);
  ushort* aggb = (ushort*)(ws + 7 * MB);
  float*  tmp  = (float*)(ws + 9 * MB);
  ushort* c0b  = (ushort*)(ws + 13 * MB);
  ushort* c1b  = (ushort*)(ws + 15 * MB);
  ushort* qkvb = (ushort*)(ws + 17 * MB);
  float*  op   = (float*)(ws + 17 * MB);    // over qkvb after attention
  float*  tmp2 = (float*)(ws + 25 * MB);    // split-K partial
  ushort* Opart = (ushort*)(ws + 5 * MB);   // 2*4MB bf16 halves
  ushort* Kt   = (ushort*)(ws + 1 * MB);    // over h (dead after GNN): 4MB
  ushort* Vt   = (ushort*)(ws + 29 * MB);   // 4MB
  ushort* aob  = (ushort*)(ws + 33 * MB);
  ushort* wlb  = (ushort*)(ws + 37 * MB);
  ushort* wrb  = (ushort*)(ws + 37 * MB + 786432);
  ushort* cvb  = (ushort*)(ws + 37 * MB + 1572864);
  ushort* ipb  = (ushort*)(ws + 37 * MB + 2752512);
  ushort* opb  = (ushort*)(ws + 37 * MB + 4325376);

  castall<<<2368, 256, 0, stream>>>(sage_wl, sage_wr, conv_w, in_proj_w, out_proj_w,
                                    wlb, wrb, cvb, ipb, opb);

  hipMemsetAsync(cnt, 0, NN * sizeof(int), stream);
  hist_kernel<<<EE / 256, 256, 0, stream>>>(ei, cnt);
  scan_kernel<<<1, 1024, 0, stream>>>(cnt, rowptr, invdeg);
  fill_kernel<<<EE / 256, 256, 0, stream>>>(ei, cnt, col);
  copycast<<<(NN * HH) / 1024, 256, 0, stream>>>(x, h, hb);

  // GNN: 6 SAGE layers (z-split dual GEMM + fused LN)
  for (int i = 0; i < 6; ++i) {
    agg_kernel<<<NN, 64, 0, stream>>>(hb, rowptr, col, invdeg, aggb);
    gemm_dual<<<dim3(64, 2, 2), 256, 0, stream>>>(
        aggb, wlb + (size_t)i * HH * HH, sage_bl + i * HH, tmp,
        hb, wrb + (size_t)i * HH * HH, tmp2);
    int do_ln = (i < 5) ? 1 : 0;
    const float* gp = do_ln ? (ln_g + i * HH) : ln_g;
    const float* bp = do_ln ? (ln_b + i * HH) : ln_b;
    ln_fuse<<<NN, 256, 0, stream>>>(tmp, tmp2, gp, bp, h, h, hb, HH, do_ln, 1, 0);
  }

  // CNN: 3 conv layers (z-split K + fused LN with prerelu)
  const ushort* cin = hb;
  ushort* couts[3] = {c0b, c1b, c0b};
  for (int j = 0; j < 3; ++j) {
    gemm_conv_mfma<<<dim3(64, 2, 2), 256, 0, stream>>>(
        cin, cvb + (size_t)j * HH * 768, conv_b + j * HH, tmp, tmp2);
    ln_fuse<<<NN, 256, 0, stream>>>(tmp, tmp2, cnorm_g + j * HH, cnorm_b + j * HH,
                                    nullptr, nullptr, couts[j], HH, 1, 0, 1);
    cin = couts[j];
  }

  // attention
  gemm_mfma<<<dim3(64, 12), 256, 0, stream>>>(
      hb, c0b, ipb, nullptr, in_proj_b, nullptr, qkvb, NN, 1536, 512, 256, 512, 0);
  kvpack<<<dim3(NN / 32, 16), 256, 0, stream>>>(qkvb, Kt, Vt);
  attn_mfma<<<dim3(NN / 128, 4, 2), 512, 0, stream>>>(qkvb, Kt, Vt, Opart, Dpart);
  attn_merge<<<(NN * 512) / 2048, 256, 0, stream>>>(Opart, Dpart, aob);

  gemm_mfma<<<dim3(64, 4), 256, 0, stream>>>(
      aob, nullptr, opb, nullptr, out_proj_b, op, nullptr, NN, 512, 512, 512, 512, 0);
  ln_fuse<<<NN, 256, 0, stream>>>(op, nullptr, anorm_g, anorm_b, nullptr, op, nullptr, 512, 1, 0, 0);
  gemm_std<<<dim3(64, 1), 256, 0, stream>>>(op, fuse_w, fuse_b, out, NN, 64, 512);
}

// Round 14
// 490.861 us; speedup vs baseline: 1.0083x; 1.0083x over previous
//
#include <hip/hip_runtime.h>

#define NN 4096
#define HH 256
#define EE 131072

__device__ __constant__ float LN_EPS = 1e-5f;
#define ATT_SCALE 0.08838834764831845f
#define ATT_SHIFT 30.0f

typedef __attribute__((ext_vector_type(8))) short bf16x8_t;
typedef __attribute__((ext_vector_type(4))) float f32x4_t;

__device__ inline ushort f2b(float f) {
  uint u = __float_as_uint(f);
  uint r = (u + 0x7FFF + ((u >> 16) & 1)) >> 16;
  return (ushort)r;
}
__device__ inline float b2f(ushort u) { return __uint_as_float((uint)u << 16); }

// ---------------- CSR build ----------------
__global__ void hist_kernel(const int* __restrict__ ei, int* __restrict__ cnt) {
  int e = blockIdx.x * blockDim.x + threadIdx.x;
  if (e < EE) atomicAdd(&cnt[ei[EE + e]], 1);
}

__global__ __launch_bounds__(1024) void scan_kernel(int* __restrict__ cnt_cursor,
                                                    int* __restrict__ rowptr,
                                                    float* __restrict__ invdeg) {
  __shared__ int part[1024];
  int t = threadIdx.x;
  int base = t * 4;
  int cs[4];
  int s = 0;
  for (int u = 0; u < 4; ++u) { cs[u] = cnt_cursor[base + u]; s += cs[u]; }
  part[t] = s;
  __syncthreads();
  for (int off = 1; off < 1024; off <<= 1) {
    int add = (t >= off) ? part[t - off] : 0;
    int v = part[t];
    __syncthreads();
    part[t] = v + add;
    __syncthreads();
  }
  int excl = (t > 0) ? part[t - 1] : 0;
  for (int u = 0; u < 4; ++u) {
    rowptr[base + u] = excl;
    cnt_cursor[base + u] = excl;
    invdeg[base + u] = 1.0f / (float)max(cs[u], 1);
    excl += cs[u];
  }
  if (t == 1023) rowptr[NN] = excl;
}

__global__ void fill_kernel(const int* __restrict__ ei, int* __restrict__ cursor,
                            int* __restrict__ col) {
  int e = blockIdx.x * blockDim.x + threadIdx.x;
  if (e < EE) {
    int d = ei[EE + e];
    int p = atomicAdd(&cursor[d], 1);
    col[p] = ei[e];
  }
}

// ---------------- all weight casts in ONE launch ----------------
__global__ __launch_bounds__(256) void castall(
    const float* __restrict__ wl, const float* __restrict__ wr,
    const float* __restrict__ cw, const float* __restrict__ ip,
    const float* __restrict__ opw,
    ushort* __restrict__ wlb, ushort* __restrict__ wrb, ushort* __restrict__ cvb,
    ushort* __restrict__ ipb, ushort* __restrict__ opb) {
  int i4 = (blockIdx.x * 256 + threadIdx.x) * 4;
  if (i4 >= 2424832) return;
  ushort4 o;
  if (i4 < 393216) {
    float4 v = *(const float4*)(wl + i4);
    o.x = f2b(v.x); o.y = f2b(v.y); o.z = f2b(v.z); o.w = f2b(v.w);
    *(ushort4*)(wlb + i4) = o;
  } else if (i4 < 786432) {
    int p = i4 - 393216;
    float4 v = *(const float4*)(wr + p);
    o.x = f2b(v.x); o.y = f2b(v.y); o.z = f2b(v.z); o.w = f2b(v.w);
    *(ushort4*)(wrb + p) = o;
  } else if (i4 < 1376256) {
    int p = i4 - 786432;
    ushort tmp[4];
#pragma unroll
    for (int u = 0; u < 4; ++u) {
      int idx = p + u;
      int j = idx / 196608;
      int rem = idx - j * 196608;
      int oc = rem / 768;
      int kk = rem - oc * 768;
      int ks = kk >> 8, ii = kk & 255;
      tmp[u] = f2b(cw[j * 196608 + oc * 768 + ii * 3 + ks]);
    }
    o.x = tmp[0]; o.y = tmp[1]; o.z = tmp[2]; o.w = tmp[3];
    *(ushort4*)(cvb + p) = o;
  } else if (i4 < 2162688) {
    int p = i4 - 1376256;
    float4 v = *(const float4*)(ip + p);
    o.x = f2b(v.x); o.y = f2b(v.y); o.z = f2b(v.z); o.w = f2b(v.w);
    *(ushort4*)(ipb + p) = o;
  } else {
    int p = i4 - 2162688;
    float4 v = *(const float4*)(opw + p);
    o.x = f2b(v.x); o.y = f2b(v.y); o.z = f2b(v.z); o.w = f2b(v.w);
    *(ushort4*)(opb + p) = o;
  }
}

// ---------------- x -> h (fp32 copy) + hb (bf16) ----------------
__global__ __launch_bounds__(256) void copycast(const float* __restrict__ x,
                                                float* __restrict__ h,
                                                ushort* __restrict__ hb) {
  int i4 = (blockIdx.x * 256 + threadIdx.x) * 4;
  float4 v = *(const float4*)(x + i4);
  *(float4*)(h + i4) = v;
  ushort4 w;
  w.x = f2b(v.x); w.y = f2b(v.y); w.z = f2b(v.z); w.w = f2b(v.w);
  *(ushort4*)(hb + i4) = w;
}

// ---------------- neighbor mean aggregation (bf16 in, fp32 acc, bf16 out) ----------------
__global__ __launch_bounds__(64) void agg_kernel(const ushort* __restrict__ hb,
                                                 const int* __restrict__ rowptr,
                                                 const int* __restrict__ col,
                                                 const float* __restrict__ invdeg,
                                                 ushort* __restrict__ aggb) {
  int n = blockIdx.x;
  int t = threadIdx.x;
  int s = rowptr[n], e = rowptr[n + 1];
  float4 acc = make_float4(0.f, 0.f, 0.f, 0.f);
  for (int j = s; j < e; ++j) {
    int c = col[j];
    ushort4 v = *(const ushort4*)(hb + (size_t)c * HH + t * 4);
    acc.x += b2f(v.x); acc.y += b2f(v.y); acc.z += b2f(v.z); acc.w += b2f(v.w);
  }
  float id = invdeg[n];
  ushort4 w;
  w.x = f2b(acc.x * id); w.y = f2b(acc.y * id);
  w.z = f2b(acc.z * id); w.w = f2b(acc.w * id);
  *(ushort4*)(aggb + (size_t)n * HH + t * 4) = w;
}

// ---------------- bf16 MFMA GEMM: C[M,Nn] = A[M,K] B[Nn,K]^T + bias ----------------
__global__ __launch_bounds__(256) void gemm_mfma(
    const ushort* __restrict__ A0, const ushort* __restrict__ A1,
    const ushort* __restrict__ B0, const ushort* __restrict__ B1,
    const float* __restrict__ bias, float* __restrict__ Cf, ushort* __restrict__ Cb,
    int M, int Nn, int K, int KHA, int KHB, int relu) {
  __shared__ ushort Alds[64][40];
  __shared__ ushort Blds[128][40];
  int t = threadIdx.x;
  int w = t >> 6, l = t & 63, quad = l >> 4, lr = l & 15;
  int wm = w & 1, wn = w >> 1;
  int m0 = blockIdx.x * 64, n0 = blockIdx.y * 128;
  int sr = t >> 2, sc8 = (t & 3) * 8;
  f32x4_t acc[2][4];
#pragma unroll
  for (int s = 0; s < 2; ++s)
#pragma unroll
    for (int q = 0; q < 4; ++q) acc[s][q] = (f32x4_t){0.f, 0.f, 0.f, 0.f};

  for (int k0 = 0; k0 < K; k0 += 32) {
    int kk = k0 + sc8;
    const ushort* ap = (kk < KHA) ? (A0 + (size_t)(m0 + sr) * KHA + kk)
                                  : (A1 + (size_t)(m0 + sr) * (K - KHA) + (kk - KHA));
    uint4 av = *(const uint4*)ap;
    const ushort* bp0 = (kk < KHB) ? (B0 + (size_t)(n0 + sr) * KHB + kk)
                                   : (B1 + (size_t)(n0 + sr) * (K - KHB) + (kk - KHB));
    uint4 bv0 = *(const uint4*)bp0;
    const ushort* bp1 = (kk < KHB) ? (B0 + (size_t)(n0 + 64 + sr) * KHB + kk)
                                   : (B1 + (size_t)(n0 + 64 + sr) * (K - KHB) + (kk - KHB));
    uint4 bv1 = *(const uint4*)bp1;
    __syncthreads();
    *(uint4*)&Alds[sr][sc8] = av;
    *(uint4*)&Blds[sr][sc8] = bv0;
    *(uint4*)&Blds[64 + sr][sc8] = bv1;
    __syncthreads();
    bf16x8_t af[2], bf[4];
#pragma unroll
    for (int s = 0; s < 2; ++s)
      af[s] = *(const bf16x8_t*)&Alds[wm * 32 + s * 16 + lr][quad * 8];
#pragma unroll
    for (int q = 0; q < 4; ++q)
      bf[q] = *(const bf16x8_t*)&Blds[wn * 64 + q * 16 + lr][quad * 8];
#pragma unroll
    for (int s = 0; s < 2; ++s)
#pragma unroll
      for (int q = 0; q < 4; ++q)
        acc[s][q] = __builtin_amdgcn_mfma_f32_16x16x32_bf16(af[s], bf[q], acc[s][q], 0, 0, 0);
  }
#pragma unroll
  for (int s = 0; s < 2; ++s) {
#pragma unroll
    for (int q = 0; q < 4; ++q) {
      int n = n0 + wn * 64 + q * 16 + lr;
      float bb = bias[n];
#pragma unroll
      for (int r = 0; r < 4; ++r) {
        int m = m0 + wm * 32 + s * 16 + quad * 4 + r;
        float v = acc[s][q][r] + bb;
        if (relu) v = fmaxf(v, 0.f);
        if (Cf) Cf[(size_t)m * Nn + n] = v;
        if (Cb) Cb[(size_t)m * Nn + n] = f2b(v);
      }
    }
  }
}

// ---------------- out_proj GEMM with fused attention-half merge ----------------
// A[m][k] = (b2f(O0[m][k]) + b2f(O1[m][k])) * inv_head(m, k>>7), computed in staging.
// C = A @ opb^T + bias -> op (fp32). Saves the attn_merge dispatch + aob round-trip.
__global__ __launch_bounds__(256) void gemm_opmerge(
    const ushort* __restrict__ Opart, const float* __restrict__ Dpart,
    const ushort* __restrict__ B0, const float* __restrict__ bias,
    float* __restrict__ Cf) {
  __shared__ ushort Alds[64][40];
  __shared__ ushort Blds[128][40];
  int t = threadIdx.x;
  int w = t >> 6, l = t & 63, quad = l >> 4, lr = l & 15;
  int wm = w & 1, wn = w >> 1;
  int m0 = blockIdx.x * 64, n0 = blockIdx.y * 128;
  int sr = t >> 2, sc8 = (t & 3) * 8;
  // per-thread row is fixed (m0+sr): hoist the 4 per-head inverse denominators
  int arow = m0 + sr;
  float invh[4];
#pragma unroll
  for (int hh = 0; hh < 4; ++hh)
    invh[hh] = 1.0f / (Dpart[(size_t)arow * 4 + hh] + Dpart[((size_t)NN + arow) * 4 + hh]);

  f32x4_t acc[2][4];
#pragma unroll
  for (int s = 0; s < 2; ++s)
#pragma unroll
    for (int q = 0; q < 4; ++q) acc[s][q] = (f32x4_t){0.f, 0.f, 0.f, 0.f};

  for (int k0 = 0; k0 < 512; k0 += 32) {
    int kk = k0 + sc8;
    int head = kk >> 7;
    ushort4 a0 = *(const ushort4*)(Opart + (size_t)arow * 512 + kk);
    ushort4 a1 = *(const ushort4*)(Opart + (size_t)arow * 512 + kk + 4);
    ushort4 b0v = *(const ushort4*)(Opart + ((size_t)NN + arow) * 512 + kk);
    ushort4 b1v = *(const ushort4*)(Opart + ((size_t)NN + arow) * 512 + kk + 4);
    float iv = invh[head];
    ushort4 m0v, m1v;
    m0v.x = f2b((b2f(a0.x) + b2f(b0v.x)) * iv);
    m0v.y = f2b((b2f(a0.y) + b2f(b0v.y)) * iv);
    m0v.z = f2b((b2f(a0.z) + b2f(b0v.z)) * iv);
    m0v.w = f2b((b2f(a0.w) + b2f(b0v.w)) * iv);
    m1v.x = f2b((b2f(a1.x) + b2f(b1v.x)) * iv);
    m1v.y = f2b((b2f(a1.y) + b2f(b1v.y)) * iv);
    m1v.z = f2b((b2f(a1.z) + b2f(b1v.z)) * iv);
    m1v.w = f2b((b2f(a1.w) + b2f(b1v.w)) * iv);
    uint4 bv0 = *(const uint4*)(B0 + (size_t)(n0 + sr) * 512 + kk);
    uint4 bv1 = *(const uint4*)(B0 + (size_t)(n0 + 64 + sr) * 512 + kk);
    __syncthreads();
    *(ushort4*)&Alds[sr][sc8] = m0v;
    *(ushort4*)&Alds[sr][sc8 + 4] = m1v;
    *(uint4*)&Blds[sr][sc8] = bv0;
    *(uint4*)&Blds[64 + sr][sc8] = bv1;
    __syncthreads();
    bf16x8_t af[2], bf[4];
#pragma unroll
    for (int s = 0; s < 2; ++s)
      af[s] = *(const bf16x8_t*)&Alds[wm * 32 + s * 16 + lr][quad * 8];
#pragma unroll
    for (int q = 0; q < 4; ++q)
      bf[q] = *(const bf16x8_t*)&Blds[wn * 64 + q * 16 + lr][quad * 8];
#pragma unroll
    for (int s = 0; s < 2; ++s)
#pragma unroll
      for (int q = 0; q < 4; ++q)
        acc[s][q] = __builtin_amdgcn_mfma_f32_16x16x32_bf16(af[s], bf[q], acc[s][q], 0, 0, 0);
  }
#pragma unroll
  for (int s = 0; s < 2; ++s) {
#pragma unroll
    for (int q = 0; q < 4; ++q) {
      int n = n0 + wn * 64 + q * 16 + lr;
      float bb = bias[n];
#pragma unroll
      for (int r = 0; r < 4; ++r) {
        int m = m0 + wm * 32 + s * 16 + quad * 4 + r;
        Cf[(size_t)m * 512 + n] = acc[s][q][r] + bb;
      }
    }
  }
}

// ---------------- dual independent 256x256 GEMMs (SAGE layer), z picks operand set ----------------
__global__ __launch_bounds__(256) void gemm_dual(
    const ushort* __restrict__ A0, const ushort* __restrict__ B0,
    const float* __restrict__ bias0, float* __restrict__ C0,
    const ushort* __restrict__ A1, const ushort* __restrict__ B1,
    float* __restrict__ C1) {
  __shared__ ushort Alds[64][40];
  __shared__ ushort Blds[128][40];
  int t = threadIdx.x;
  int w = t >> 6, l = t & 63, quad = l >> 4, lr = l & 15;
  int wm = w & 1, wn = w >> 1;
  int m0 = blockIdx.x * 64, n0 = blockIdx.y * 128;
  int z = blockIdx.z;
  const ushort* A = z ? A1 : A0;
  const ushort* B = z ? B1 : B0;
  float* C = z ? C1 : C0;
  int sr = t >> 2, sc8 = (t & 3) * 8;
  f32x4_t acc[2][4];
#pragma unroll
  for (int s = 0; s < 2; ++s)
#pragma unroll
    for (int q = 0; q < 4; ++q) acc[s][q] = (f32x4_t){0.f, 0.f, 0.f, 0.f};

  for (int k0 = 0; k0 < 256; k0 += 32) {
    int kk = k0 + sc8;
    uint4 av = *(const uint4*)(A + (size_t)(m0 + sr) * 256 + kk);
    uint4 bv0 = *(const uint4*)(B + (size_t)(n0 + sr) * 256 + kk);
    uint4 bv1 = *(const uint4*)(B + (size_t)(n0 + 64 + sr) * 256 + kk);
    __syncthreads();
    *(uint4*)&Alds[sr][sc8] = av;
    *(uint4*)&Blds[sr][sc8] = bv0;
    *(uint4*)&Blds[64 + sr][sc8] = bv1;
    __syncthreads();
    bf16x8_t af[2], bf[4];
#pragma unroll
    for (int s = 0; s < 2; ++s)
      af[s] = *(const bf16x8_t*)&Alds[wm * 32 + s * 16 + lr][quad * 8];
#pragma unroll
    for (int q = 0; q < 4; ++q)
      bf[q] = *(const bf16x8_t*)&Blds[wn * 64 + q * 16 + lr][quad * 8];
#pragma unroll
    for (int s = 0; s < 2; ++s)
#pragma unroll
      for (int q = 0; q < 4; ++q)
        acc[s][q] = __builtin_amdgcn_mfma_f32_16x16x32_bf16(af[s], bf[q], acc[s][q], 0, 0, 0);
  }
#pragma unroll
  for (int s = 0; s < 2; ++s) {
#pragma unroll
    for (int q = 0; q < 4; ++q) {
      int n = n0 + wn * 64 + q * 16 + lr;
      float bb = z ? 0.f : bias0[n];
#pragma unroll
      for (int r = 0; r < 4; ++r) {
        int m = m0 + wm * 32 + s * 16 + quad * 4 + r;
        C[(size_t)m * 256 + n] = acc[s][q][r] + bb;
      }
    }
  }
}

// ---------------- conv1d(k=3,pad=1) as MFMA GEMM, z-split K (2x384), raw fp32 out ----------------
__global__ __launch_bounds__(256) void gemm_conv_mfma(
    const ushort* __restrict__ Ab, const ushort* __restrict__ B,
    const float* __restrict__ bias, float* __restrict__ C0, float* __restrict__ C1) {
  __shared__ ushort Alds[64][40];
  __shared__ ushort Blds[128][40];
  int t = threadIdx.x;
  int w = t >> 6, l = t & 63, quad = l >> 4, lr = l & 15;
  int wm = w & 1, wn = w >> 1;
  int m0 = blockIdx.x * 64, n0 = blockIdx.y * 128;
  int z = blockIdx.z;
  float* C = z ? C1 : C0;
  int sr = t >> 2, sc8 = (t & 3) * 8;
  f32x4_t acc[2][4];
#pragma unroll
  for (int s = 0; s < 2; ++s)
#pragma unroll
    for (int q = 0; q < 4; ++q) acc[s][q] = (f32x4_t){0.f, 0.f, 0.f, 0.f};

  for (int k0 = 0; k0 < 384; k0 += 32) {
    int kk = z * 384 + k0 + sc8;
    int ks = kk >> 8, ii = kk & 255;
    int nr = m0 + sr + ks - 1;
    uint4 av = make_uint4(0u, 0u, 0u, 0u);
    if (nr >= 0 && nr < NN) av = *(const uint4*)(Ab + (size_t)nr * HH + ii);
    uint4 bv0 = *(const uint4*)(B + (size_t)(n0 + sr) * 768 + kk);
    uint4 bv1 = *(const uint4*)(B + (size_t)(n0 + 64 + sr) * 768 + kk);
    __syncthreads();
    *(uint4*)&Alds[sr][sc8] = av;
    *(uint4*)&Blds[sr][sc8] = bv0;
    *(uint4*)&Blds[64 + sr][sc8] = bv1;
    __syncthreads();
    bf16x8_t af[2], bf[4];
#pragma unroll
    for (int s = 0; s < 2; ++s)
      af[s] = *(const bf16x8_t*)&Alds[s * 16 + wm * 32 + lr][quad * 8];
#pragma unroll
    for (int q = 0; q < 4; ++q)
      bf[q] = *(const bf16x8_t*)&Blds[wn * 64 + q * 16 + lr][quad * 8];
#pragma unroll
    for (int s = 0; s < 2; ++s)
#pragma unroll
      for (int q = 0; q < 4; ++q)
        acc[s][q] = __builtin_amdgcn_mfma_f32_16x16x32_bf16(af[s], bf[q], acc[s][q], 0, 0, 0);
  }
#pragma unroll
  for (int s = 0; s < 2; ++s) {
#pragma unroll
    for (int q = 0; q < 4; ++q) {
      int n = n0 + wn * 64 + q * 16 + lr;
      float bb = z ? 0.f : bias[n];
#pragma unroll
      for (int r = 0; r < 4; ++r) {
        int m = m0 + wm * 32 + s * 16 + quad * 4 + r;
        C[(size_t)m * HH + n] = acc[s][q][r] + bb;
      }
    }
  }
}

// ---------------- fp32 tiled GEMM (fuse head only) ----------------
__global__ __launch_bounds__(256) void gemm_std(
    const float* __restrict__ A0, const float* __restrict__ B0,
    const float* __restrict__ bias, float* __restrict__ C,
    int M, int Nn, int K) {
  __shared__ float As[16][68];
  __shared__ float Bs[16][68];
  int t = threadIdx.x;
  int m0 = blockIdx.x * 64, n0 = blockIdx.y * 64;
  int ty = t >> 4, tx = t & 15;
  int lr = t >> 2, lc4 = (t & 3) * 4;
  float acc[4][4] = {};
  for (int k0 = 0; k0 < K; k0 += 16) {
    int kk = k0 + lc4;
    float4 va = *(const float4*)(A0 + (size_t)(m0 + lr) * K + kk);
    As[lc4 + 0][lr] = va.x; As[lc4 + 1][lr] = va.y;
    As[lc4 + 2][lr] = va.z; As[lc4 + 3][lr] = va.w;
    float4 vb = *(const float4*)(B0 + (size_t)(n0 + lr) * K + kk);
    Bs[lc4 + 0][lr] = vb.x; Bs[lc4 + 1][lr] = vb.y;
    Bs[lc4 + 2][lr] = vb.z; Bs[lc4 + 3][lr] = vb.w;
    __syncthreads();
#pragma unroll
    for (int k = 0; k < 16; ++k) {
      float4 a4 = *(const float4*)&As[k][4 * ty];
      float4 b4 = *(const float4*)&Bs[k][4 * tx];
      float av[4] = {a4.x, a4.y, a4.z, a4.w};
      float bv[4] = {b4.x, b4.y, b4.z, b4.w};
#pragma unroll
      for (int i = 0; i < 4; ++i)
#pragma unroll
        for (int j = 0; j < 4; ++j) acc[i][j] += av[i] * bv[j];
    }
    __syncthreads();
  }
#pragma unroll
  for (int i = 0; i < 4; ++i) {
    int m = m0 + 4 * ty + i;
    float o[4];
#pragma unroll
    for (int j = 0; j < 4; ++j) o[j] = acc[i][j] + bias[n0 + 4 * tx + j];
    float4 o4 = make_float4(o[0], o[1], o[2], o[3]);
    *(float4*)(C + (size_t)m * Nn + n0 + 4 * tx) = o4;
  }
}

// ---------------- fused LayerNorm (+ x2 sum + pre-relu + optional relu+residual) ----------------
__global__ __launch_bounds__(256) void ln_fuse(
    const float* __restrict__ x, const float* __restrict__ x2,
    const float* __restrict__ g, const float* __restrict__ b,
    const float* __restrict__ res, float* __restrict__ outf, ushort* __restrict__ outb,
    int D, int do_ln, int relu_res, int prerelu) {
  int row = blockIdx.x, t = threadIdx.x;
  int nv = D >> 8;
  float vals[2];
  float s = 0.f, sq = 0.f;
  for (int u = 0; u < nv; ++u) {
    int c = t + (u << 8);
    float v = x[(size_t)row * D + c];
    if (x2) v += x2[(size_t)row * D + c];
    if (prerelu) v = fmaxf(v, 0.f);
    vals[u] = v; s += v; sq += v * v;
  }
  __shared__ float red[8];
  float m = 0.f, inv = 1.f;
  if (do_ln) {
    for (int off = 32; off >= 1; off >>= 1) {
      s += __shfl_xor(s, off);
      sq += __shfl_xor(sq, off);
    }
    int wid = t >> 6;
    if ((t & 63) == 0) { red[wid] = s; red[4 + wid] = sq; }
    __syncthreads();
    if (t == 0) {
      float S = red[0] + red[1] + red[2] + red[3];
      float Q = red[4] + red[5] + red[6] + red[7];
      float mm = S / D;
      float vv = Q / D - mm * mm;
      red[0] = mm;
      red[1] = rsqrtf(vv + LN_EPS);
    }
    __syncthreads();
    m = red[0]; inv = red[1];
  }
  for (int u = 0; u < nv; ++u) {
    int c = t + (u << 8);
    float y = vals[u];
    if (do_ln) y = (y - m) * inv * g[c] + b[c];
    if (relu_res) y = fmaxf(y, 0.f) + res[(size_t)row * D + c];
    if (outf) outf[(size_t)row * D + c] = y;
    if (outb) outb[(size_t)row * D + c] = f2b(y);
  }
}

// ---------------- K/V repack for shared-K attention ----------------
// Kt[head][kt] = 8KB tile, fragment-packed LANE-LINEAR: frag (ks,ct) at ushort
// offset (ks*2+ct)*512 + l*8 holds K[key=n0+ct*16+(l&15)][head*128+ks*32+(l>>4)*8..+8].
// VtT[head][kt][dl][key32] unchanged (1KB contiguous per dt fragment).
__global__ __launch_bounds__(256) void kvpack(const ushort* __restrict__ qkvb,
                                              ushort* __restrict__ Kt,
                                              ushort* __restrict__ VtT) {
  int t = threadIdx.x;
  int n0 = blockIdx.x * 32;
  int by = blockIdx.y;
  int kt = n0 >> 5;
  // K repack (lane-linear fragments)
  {
    int head = by >> 2, ks = by & 3;
    int key5 = t >> 3;            // 0..31
    int ct = key5 >> 4, lr = key5 & 15;
    int e8 = t & 7;
    int quad = e8 >> 1, h4 = (e8 & 1) * 4;
    uint2 v = *(const uint2*)(qkvb + (size_t)(n0 + key5) * 1536 + 512 + head * 128 +
                              ks * 32 + quad * 8 + h4);
    int l = quad * 16 + lr;
    *(uint2*)(Kt + (((size_t)head * 128 + kt) << 12) + (ks * 2 + ct) * 512 + l * 8 + h4) = v;
  }
  // V transpose (unchanged)
  __shared__ ushort tile[32][34];
  int d0 = by * 32;
  int tx = t & 31, ty = t >> 5;
#pragma unroll
  for (int u = 0; u < 4; ++u) {
    int r = ty + 8 * u;
    tile[r][tx] = qkvb[(size_t)(n0 + r) * 1536 + 1024 + d0 + tx];
  }
  __syncthreads();
#pragma unroll
  for (int u = 0; u < 4; ++u) {
    int dg = d0 + ty + 8 * u;
    int head = dg >> 7, dl = dg & 127;
    VtT[((((size_t)head * 128 + kt) * 128 + dl) << 5) + tx] = tile[tx][ty + 8 * u];
  }
}

// ---------------- bf16 MFMA flash attention (R11 version, proven 58.4us) ----------------
// Qb=64 shared-K: block=4 waves covers 64 q-rows; wave w owns q-rows [16w,+16) for
// QK/softmax and d-cols [32w,+32) for PV. K-tile (8KB) staged ONCE per block into
// double-buffered LDS (register prefetch, commit after PV); P shared via LDS.
// V fragment-direct per wave. Fixed-shift softmax; z-split halves merge by addition.
__global__ __launch_bounds__(256, 2) void attn_mfma(const ushort* __restrict__ qkvb,
                                                    const ushort* __restrict__ Kt,
                                                    const ushort* __restrict__ VtT,
                                                    ushort* __restrict__ Opart,
                                                    float* __restrict__ Dpart) {
  __shared__ __align__(16) char smem[21760];  // Kl[2][4096]u (16KB) + Psh[4][16][40]u (5120B)
  ushort* Kl = (ushort*)smem;
  ushort* Psh = (ushort*)(smem + 16384);
  int t = threadIdx.x;
  int w = t >> 6, l = t & 63;
  int quad = l >> 4, lr = l & 15;
  int head = blockIdx.y;
  int z = blockIdx.z;
  int q0 = blockIdx.x * 64;

  // Q fragments: wave w's 16 rows x 4 k-slices
  bf16x8_t qf[4];
#pragma unroll
  for (int ks = 0; ks < 4; ++ks)
    qf[ks] = *(const bf16x8_t*)(qkvb + (size_t)(q0 + w * 16 + lr) * 1536 +
                                head * 128 + ks * 32 + quad * 8);

  f32x4_t of[4][2];  // O[rc*16 rows][w*32 + u*16 cols]
#pragma unroll
  for (int rc = 0; rc < 4; ++rc)
#pragma unroll
    for (int u = 0; u < 2; ++u) of[rc][u] = (f32x4_t){0.f, 0.f, 0.f, 0.f};
  float den[4] = {0.f, 0.f, 0.f, 0.f};

  const size_t hk = (size_t)head * 128;
  // prologue: stage first K tile into Kl[0]
  {
    const ushort* kb = Kt + ((hk + z * 64) << 12) + t * 16;
    uint4 a0 = *(const uint4*)kb;
    uint4 a1 = *(const uint4*)(kb + 8);
    *(uint4*)(Kl + t * 16) = a0;
    *(uint4*)(Kl + t * 16 + 8) = a1;
  }
  __syncthreads();
  int cur = 0;

  for (int tt = 0; tt < 64; ++tt) {
    int kt = z * 64 + tt;
    // prefetch next K tile into registers (8 VGPR; committed after PV)
    uint4 k0, k1;
    if (tt < 63) {
      const ushort* kb = Kt + ((hk + kt + 1) << 12) + t * 16;
      k0 = *(const uint4*)kb;
      k1 = *(const uint4*)(kb + 8);
    }
    // V fragments for this wave's d-slice (global, 1KB coalesced each)
    const ushort* vbase = VtT + ((hk + kt) << 12);
    bf16x8_t vf[2];
#pragma unroll
    for (int u = 0; u < 2; ++u)
      vf[u] = *(const bf16x8_t*)(vbase + (w * 2 + u) * 512 + lr * 32 + quad * 8);

    // QK^T: S[w's 16 rows][32 keys]
    f32x4_t sf[2];
    sf[0] = (f32x4_t){0.f, 0.f, 0.f, 0.f};
    sf[1] = (f32x4_t){0.f, 0.f, 0.f, 0.f};
    __builtin_amdgcn_s_setprio(1);
#pragma unroll
    for (int ks = 0; ks < 4; ++ks)
#pragma unroll
      for (int ct = 0; ct < 2; ++ct) {
        bf16x8_t kf = *(const bf16x8_t*)(Kl + cur * 4096 + (ks * 2 + ct) * 512 + l * 8);
        sf[ct] = __builtin_amdgcn_mfma_f32_16x16x32_bf16(qf[ks], kf, sf[ct], 0, 0, 0);
      }
    __builtin_amdgcn_s_setprio(0);

    // softmax exp (fixed shift): P -> shared LDS, den partials
#pragma unroll
    for (int ct = 0; ct < 2; ++ct)
#pragma unroll
      for (int r = 0; r < 4; ++r) {
        float e = __expf(sf[ct][r] * ATT_SCALE - ATT_SHIFT);
        Psh[w * 640 + (quad * 4 + r) * 40 + ct * 16 + lr] = f2b(e);
        den[r] += e;
      }
    __syncthreads();  // P visible to all waves; all waves done reading Kl[cur]

    // PV: O[all 64 rows][w's 32 cols] += P * V
    __builtin_amdgcn_s_setprio(1);
#pragma unroll
    for (int rc = 0; rc < 4; ++rc) {
      bf16x8_t pf = *(const bf16x8_t*)(Psh + rc * 640 + lr * 40 + quad * 8);
#pragma unroll
      for (int u = 0; u < 2; ++u)
        of[rc][u] = __builtin_amdgcn_mfma_f32_16x16x32_bf16(pf, vf[u], of[rc][u], 0, 0, 0);
    }
    __builtin_amdgcn_s_setprio(0);

    // commit prefetched K to the other LDS buffer
    if (tt < 63) {
      *(uint4*)(Kl + (cur ^ 1) * 4096 + t * 16) = k0;
      *(uint4*)(Kl + (cur ^ 1) * 4096 + t * 16 + 8) = k1;
    }
    __syncthreads();  // Kl[nxt] ready; Psh consumed (safe to overwrite next iter)
    cur ^= 1;
  }

  // den: reduce over the 16 lr lanes (rows quad*4+r of wave w)
#pragma unroll
  for (int mask = 1; mask < 16; mask <<= 1)
#pragma unroll
    for (int r = 0; r < 4; ++r) den[r] += __shfl_xor(den[r], mask);
  if (lr == 0) {
#pragma unroll
    for (int r = 0; r < 4; ++r)
      Dpart[((size_t)z * NN + q0 + w * 16 + quad * 4 + r) * 4 + head] = den[r];
  }
  // O partial write: each (row, col) owned by exactly one (wave, lane)
#pragma unroll
  for (int rc = 0; rc < 4; ++rc)
#pragma unroll
    for (int u = 0; u < 2; ++u)
#pragma unroll
      for (int r = 0; r < 4; ++r) {
        int row = q0 + rc * 16 + quad * 4 + r;
        int colg = head * 128 + w * 32 + u * 16 + lr;
        Opart[((size_t)z * NN + row) * 512 + colg] = f2b(of[rc][u][r]);
      }
}

// ---------------- launch ----------------
extern "C" void kernel_launch(void* const* d_in, const int* in_sizes, int n_in,
                              void* d_out, int out_size, void* d_ws, size_t ws_size,
                              hipStream_t stream) {
  const float* x          = (const float*)d_in[0];
  const int*   ei         = (const int*)d_in[1];
  const float* sage_wl    = (const float*)d_in[2];
  const float* sage_wr    = (const float*)d_in[3];
  const float* sage_bl    = (const float*)d_in[4];
  const float* ln_g       = (const float*)d_in[5];
  const float* ln_b       = (const float*)d_in[6];
  const float* conv_w     = (const float*)d_in[7];
  const float* conv_b     = (const float*)d_in[8];
  const float* cnorm_g    = (const float*)d_in[9];
  const float* cnorm_b    = (const float*)d_in[10];
  const float* in_proj_w  = (const float*)d_in[11];
  const float* in_proj_b  = (const float*)d_in[12];
  const float* out_proj_w = (const float*)d_in[13];
  const float* out_proj_b = (const float*)d_in[14];
  const float* anorm_g    = (const float*)d_in[15];
  const float* anorm_b    = (const float*)d_in[16];
  const float* fuse_w     = (const float*)d_in[17];
  const float* fuse_b     = (const float*)d_in[18];
  float* out = (float*)d_out;

  char* ws = (char*)d_ws;
  const size_t MB = 1 << 20;
  int*    rowptr = (int*)(ws + 0);
  int*    cnt    = (int*)(ws + 65536);
  int*    col    = (int*)(ws + 131072);
  float*  invdeg = (float*)(ws + 786432);
  float*  Dpart  = (float*)(ws + 802816);   // 2*4096*4*4B = 128KB
  float*  h    = (float*)(ws + 1 * MB);
  ushort* hb   = (ushort*)(ws + 5 * MB);
  ushort* aggb = (ushort*)(ws + 7 * MB);
  float*  tmp  = (float*)(ws + 9 * MB);
  ushort* c0b  = (ushort*)(ws + 13 * MB);
  ushort* c1b  = (ushort*)(ws + 15 * MB);
  ushort* qkvb = (ushort*)(ws + 17 * MB);
  float*  op   = (float*)(ws + 17 * MB);    // over qkvb after attention
  float*  tmp2 = (float*)(ws + 25 * MB);    // split-K partial
  ushort* Opart = (ushort*)(ws + 5 * MB);   // 2*4MB bf16 halves
  ushort* Kt   = (ushort*)(ws + 1 * MB);    // over h (dead after GNN): 4MB
  ushort* Vt   = (ushort*)(ws + 29 * MB);   // 4MB
  ushort* wlb  = (ushort*)(ws + 37 * MB);
  ushort* wrb  = (ushort*)(ws + 37 * MB + 786432);
  ushort* cvb  = (ushort*)(ws + 37 * MB + 1572864);
  ushort* ipb  = (ushort*)(ws + 37 * MB + 2752512);
  ushort* opb  = (ushort*)(ws + 37 * MB + 4325376);

  castall<<<2368, 256, 0, stream>>>(sage_wl, sage_wr, conv_w, in_proj_w, out_proj_w,
                                    wlb, wrb, cvb, ipb, opb);

  hipMemsetAsync(cnt, 0, NN * sizeof(int), stream);
  hist_kernel<<<EE / 256, 256, 0, stream>>>(ei, cnt);
  scan_kernel<<<1, 1024, 0, stream>>>(cnt, rowptr, invdeg);
  fill_kernel<<<EE / 256, 256, 0, stream>>>(ei, cnt, col);
  copycast<<<(NN * HH) / 1024, 256, 0, stream>>>(x, h, hb);

  // GNN: 6 SAGE layers (z-split dual GEMM + fused LN)
  for (int i = 0; i < 6; ++i) {
    agg_kernel<<<NN, 64, 0, stream>>>(hb, rowptr, col, invdeg, aggb);
    gemm_dual<<<dim3(64, 2, 2), 256, 0, stream>>>(
        aggb, wlb + (size_t)i * HH * HH, sage_bl + i * HH, tmp,
        hb, wrb + (size_t)i * HH * HH, tmp2);
    int do_ln = (i < 5) ? 1 : 0;
    const float* gp = do_ln ? (ln_g + i * HH) : ln_g;
    const float* bp = do_ln ? (ln_b + i * HH) : ln_b;
    ln_fuse<<<NN, 256, 0, stream>>>(tmp, tmp2, gp, bp, h, h, hb, HH, do_ln, 1, 0);
  }

  // CNN: 3 conv layers (z-split K + fused LN with prerelu)
  const ushort* cin = hb;
  ushort* couts[3] = {c0b, c1b, c0b};
  for (int j = 0; j < 3; ++j) {
    gemm_conv_mfma<<<dim3(64, 2, 2), 256, 0, stream>>>(
        cin, cvb + (size_t)j * HH * 768, conv_b + j * HH, tmp, tmp2);
    ln_fuse<<<NN, 256, 0, stream>>>(tmp, tmp2, cnorm_g + j * HH, cnorm_b + j * HH,
                                    nullptr, nullptr, couts[j], HH, 1, 0, 1);
    cin = couts[j];
  }

  // attention
  gemm_mfma<<<dim3(64, 12), 256, 0, stream>>>(
      hb, c0b, ipb, nullptr, in_proj_b, nullptr, qkvb, NN, 1536, 512, 256, 512, 0);
  kvpack<<<dim3(NN / 32, 16), 256, 0, stream>>>(qkvb, Kt, Vt);
  attn_mfma<<<dim3(NN / 64, 4, 2), 256, 0, stream>>>(qkvb, Kt, Vt, Opart, Dpart);

  // out_proj with fused half-merge (replaces attn_merge + gemm_mfma)
  gemm_opmerge<<<dim3(64, 4), 256, 0, stream>>>(Opart, Dpart, opb, out_proj_b, op);
  ln_fuse<<<NN, 256, 0, stream>>>(op, nullptr, anorm_g, anorm_b, nullptr, op, nullptr, 512, 1, 0, 0);
  gemm_std<<<dim3(64, 1), 256, 0, stream>>>(op, fuse_w, fuse_b, out, NN, 64, 512);
}